// Round 6
// baseline (280.623 us; speedup 1.0000x reference)
//
#include <hip/hip_runtime.h>
#include <hip/hip_bf16.h>
#include <math.h>

typedef __bf16 bf16;
typedef __bf16 bf16x4 __attribute__((ext_vector_type(4)));
typedef __bf16 bf16x8 __attribute__((ext_vector_type(8)));
typedef float  f32x4  __attribute__((ext_vector_type(4)));
typedef float  f32x16 __attribute__((ext_vector_type(16)));

#define B_  4
#define S_  2048
#define D_  1024
#define H_  16
#define DH  64
#define M_  (B_*S_)      // 8192
#define BH_ (B_*H_)      // 64

// 1/sqrt(64) * log2(e): folded into Q so attn uses exp2 directly
#define QSCALE 0.18033688011112042f

__device__ __forceinline__ void glds16(const bf16* g, bf16* l) {
  __builtin_amdgcn_global_load_lds((const __attribute__((address_space(1))) void*)g,
                                   (__attribute__((address_space(3))) void*)l, 16, 0, 0);
}

// -------------------- fp32 -> bf16 convert --------------------
__global__ void cvt_f32_bf16(const float* __restrict__ in, bf16* __restrict__ out, int n) {
  int i = (blockIdx.x * 256 + threadIdx.x) * 4;
  if (i < n) {
    float4 v = *(const float4*)(in + i);
    bf16x4 o = { (bf16)v.x, (bf16)v.y, (bf16)v.z, (bf16)v.w };
    *(bf16x4*)(out + i) = o;
  }
}

// -------------------- fp32 -> bf16 transpose: both weight matrices, one launch --------------------
// bx < 96: w_qkv (1024x3072); else: w_out (1024x1024)
__global__ void transpose_cvt2(const float* __restrict__ wqkv, const float* __restrict__ wout,
                               bf16* __restrict__ wqkvT, bf16* __restrict__ woutT) {
  __shared__ float tile[32][33];
  int bx = blockIdx.x;
  const float* in; bf16* out; int C, c0;
  if (bx < 96) { in = wqkv; out = wqkvT; C = 3072; c0 = bx * 32; }
  else         { in = wout; out = woutT; C = 1024; c0 = (bx - 96) * 32; }
  int tx = threadIdx.x, ty = threadIdx.y;
  int r0 = blockIdx.y * 32;
  #pragma unroll
  for (int i = ty; i < 32; i += 8) tile[i][tx] = in[(size_t)(r0 + i) * C + c0 + tx];
  __syncthreads();
  #pragma unroll
  for (int i = ty; i < 32; i += 8) out[(size_t)(c0 + i) * D_ + r0 + tx] = (bf16)tile[tx][i];
}

// -------------------- GEMM core (32x32x16 MFMA): C[128x128] += A[128xK]*Bt[128xK]^T ----------
// glds16 staging with XOR chunk-swizzle: LDS slot s of row m holds global chunk s^(m&3),
// so 32x32 A/B-frag reads (addr ((2t+x)^(m&3))*8) hit 8 distinct 4-bank starts -> conflict-free
// on the unpadded (glds-compatible) LDA2=32 layout. 8 MFMA@8cyc + 8 ds_read_b128 per BK=32.
#define LDA2 32

__device__ __forceinline__ void gemm_core32(const bf16* __restrict__ A, const bf16* __restrict__ Bt,
                                            int m0, int n0, bf16* As, bf16* Bs,
                                            int tid, f32x16 acc[2][2]) {
  int wave = tid >> 6, lane = tid & 63;
  int wm = (wave >> 1) * 64, wn = (wave & 1) * 64;
  int l32 = lane & 31, x = lane >> 5;
  // staging: lane covers LDS (row=lane>>2, slot=lane&3); fetch global chunk slot^(row&3)
  int lr = lane >> 2;
  int gch = (lane & 3) ^ (lr & 3);
  const bf16* gA = A  + (size_t)(m0 + wave * 32 + lr) * D_ + gch * 8;
  const bf16* gB = Bt + (size_t)(n0 + wave * 32 + lr) * D_ + gch * 8;
  bf16* lA = As + wave * 32 * LDA2;
  bf16* lB = Bs + wave * 32 * LDA2;
  // loop-invariant fragment offsets [kstep t][tile]
  int aoff[2][2], boff[2][2];
  #pragma unroll
  for (int t = 0; t < 2; t++)
    #pragma unroll
    for (int i = 0; i < 2; i++) {
      aoff[t][i] = (wm + i * 32 + l32) * LDA2 + (((2 * t + x) ^ (l32 & 3)) * 8);
      boff[t][i] = (wn + i * 32 + l32) * LDA2 + (((2 * t + x) ^ (l32 & 3)) * 8);
    }
  for (int k0 = 0; k0 < D_; k0 += 32) {
    glds16(gA + k0,           lA);
    glds16(gA + k0 + 16 * D_, lA + 16 * LDA2);
    glds16(gB + k0,           lB);
    glds16(gB + k0 + 16 * D_, lB + 16 * LDA2);
    __syncthreads();
    #pragma unroll
    for (int t = 0; t < 2; t++) {
      bf16x8 af[2], bff[2];
      #pragma unroll
      for (int i = 0; i < 2; i++) af[i]  = *(const bf16x8*)(As + aoff[t][i]);
      #pragma unroll
      for (int j = 0; j < 2; j++) bff[j] = *(const bf16x8*)(Bs + boff[t][j]);
      #pragma unroll
      for (int i = 0; i < 2; i++)
        #pragma unroll
        for (int j = 0; j < 2; j++)
          acc[i][j] = __builtin_amdgcn_mfma_f32_32x32x16_bf16(af[i], bff[j], acc[i][j], 0, 0, 0);
    }
    __syncthreads();
  }
}

// GEMM1: qkv = hidden @ w_qkv. Q gets QSCALE folded in; V written transposed.
// 32x32 C/D layout: col = lane&31, row = (reg&3) + 8*(reg>>2) + 4*(lane>>5).
__global__ __launch_bounds__(256) void gemm_qkv(const bf16* __restrict__ A, const bf16* __restrict__ Bt,
                                                bf16* __restrict__ Qb, bf16* __restrict__ Kb,
                                                bf16* __restrict__ Vtb) {
  __shared__ __attribute__((aligned(16))) bf16 As[128 * LDA2];
  __shared__ __attribute__((aligned(16))) bf16 Bs[128 * LDA2];
  int tid = threadIdx.x;
  int m0 = blockIdx.y * 128, n0 = blockIdx.x * 128;
  f32x16 acc[2][2] = {};
  gemm_core32(A, Bt, m0, n0, As, Bs, tid, acc);
  int wave = tid >> 6, lane = tid & 63;
  int wm = (wave >> 1) * 64, wn = (wave & 1) * 64;
  int l32 = lane & 31, x = lane >> 5;
  int which = n0 >> 10;                 // 0=Q 1=K 2=V, block-uniform
  if (which == 2) {
    #pragma unroll
    for (int i = 0; i < 2; i++) {
      #pragma unroll
      for (int j = 0; j < 2; j++) {
        int n = n0 + wn + j * 32 + l32;
        int h = (n >> 6) & 15, dd = n & 63;
        #pragma unroll
        for (int g = 0; g < 4; g++) {
          int mb = m0 + wm + i * 32 + 8 * g + 4 * x;   // rows mb..mb+3 = regs 4g..4g+3
          int b = mb >> 11, s = mb & 2047;
          bf16x4 v4 = { (bf16)acc[i][j][4*g], (bf16)acc[i][j][4*g+1],
                        (bf16)acc[i][j][4*g+2], (bf16)acc[i][j][4*g+3] };
          *(bf16x4*)(Vtb + ((size_t)(b * H_ + h) * DH + dd) * S_ + s) = v4;
        }
      }
    }
  } else {
    bf16* dst = (which == 0) ? Qb : Kb;
    float sc = (which == 0) ? QSCALE : 1.0f;
    #pragma unroll
    for (int i = 0; i < 2; i++) {
      #pragma unroll
      for (int j = 0; j < 2; j++) {
        int n = n0 + wn + j * 32 + l32;
        int h = (n >> 6) & 15, dd = n & 63;
        #pragma unroll
        for (int reg = 0; reg < 16; reg++) {
          int m = m0 + wm + i * 32 + (reg & 3) + 8 * (reg >> 2) + 4 * x;
          int b = m >> 11, s = m & 2047;
          dst[(((size_t)(b * H_ + h)) * S_ + s) * DH + dd] = (bf16)(acc[i][j][reg] * sc);
        }
      }
    }
  }
}

// GEMM2: out = ctx @ w_out, fp32 output
__global__ __launch_bounds__(256) void gemm_out(const bf16* __restrict__ A, const bf16* __restrict__ Bt,
                                                float* __restrict__ C) {
  __shared__ __attribute__((aligned(16))) bf16 As[128 * LDA2];
  __shared__ __attribute__((aligned(16))) bf16 Bs[128 * LDA2];
  int tid = threadIdx.x;
  int m0 = blockIdx.y * 128, n0 = blockIdx.x * 128;
  f32x16 acc[2][2] = {};
  gemm_core32(A, Bt, m0, n0, As, Bs, tid, acc);
  int wave = tid >> 6, lane = tid & 63;
  int wm = (wave >> 1) * 64, wn = (wave & 1) * 64;
  int l32 = lane & 31, x = lane >> 5;
  #pragma unroll
  for (int i = 0; i < 2; i++)
    #pragma unroll
    for (int j = 0; j < 2; j++) {
      int n = n0 + wn + j * 32 + l32;
      #pragma unroll
      for (int reg = 0; reg < 16; reg++) {
        int m = m0 + wm + i * 32 + (reg & 3) + 8 * (reg >> 2) + 4 * x;
        C[(size_t)m * D_ + n] = acc[i][j][reg];
      }
    }
}

// -------------------- flash attention (unchanged from R5: 84us, LDS-bound) --------------------
#define LDK 72   // K/V tiles: 144B rows
#define LDP 40   // Ps half-panels: 80B rows
#define NT  (S_ / 64)

__global__ __launch_bounds__(256, 2) void attn(const bf16* __restrict__ Qb, const bf16* __restrict__ Kb,
                                               const bf16* __restrict__ Vtb, bf16* __restrict__ ctx) {
  __shared__ __attribute__((aligned(16))) bf16 Ks[2][64 * LDK];   // [buf][key][dd]
  __shared__ __attribute__((aligned(16))) bf16 Vs[2][64 * LDK];   // [buf][dd][key]
  __shared__ __attribute__((aligned(16))) bf16 Ps[4][64 * LDP];   // per-wave P half: [q(64)][key(32)]
  int tid = threadIdx.x;
  int wave = tid >> 6, lane = tid & 63, quad = lane >> 4, l16 = lane & 15;
  int bh = blockIdx.x;                  // x-major: XCD = bh % 8 -> K/V working set stays in one L2
  int b = bh >> 4, h = bh & 15;
  int q0 = blockIdx.y * 256 + wave * 64;
  const bf16* Qp = Qb  + (size_t)bh * S_ * DH;
  const bf16* Kp = Kb  + (size_t)bh * S_ * DH;
  const bf16* Vp = Vtb + (size_t)bh * DH * S_;

  int srow = tid >> 3, scc = (tid & 7) << 3;

  bf16x8 qf[4][2];
  #pragma unroll
  for (int nq = 0; nq < 4; nq++)
    #pragma unroll
    for (int ks = 0; ks < 2; ks++)
      qf[nq][ks] = *(const bf16x8*)(Qp + (size_t)(q0 + nq * 16 + l16) * DH + ks * 32 + quad * 8);

  bf16 one1 = (bf16)1.0f;
  bf16x8 onesf = { one1, one1, one1, one1, one1, one1, one1, one1 };

  f32x4 o[4][4] = {};       // o[nq][td]: row q = quad*4+r, col dd = td*16+l16
  f32x4 oden[4] = {};       // denom(q), same row mapping

  {
    bf16x8 k0a = *(const bf16x8*)(Kp + (size_t)srow * DH + scc);
    bf16x8 k0b = *(const bf16x8*)(Kp + (size_t)(32 + srow) * DH + scc);
    bf16x8 v0a = *(const bf16x8*)(Vp + (size_t)srow * S_ + scc);
    bf16x8 v0b = *(const bf16x8*)(Vp + (size_t)(32 + srow) * S_ + scc);
    *(bf16x8*)(Ks[0] + srow * LDK + scc)        = k0a;
    *(bf16x8*)(Ks[0] + (32 + srow) * LDK + scc) = k0b;
    *(bf16x8*)(Vs[0] + srow * LDK + scc)        = v0a;
    *(bf16x8*)(Vs[0] + (32 + srow) * LDK + scc) = v0b;
  }

  for (int kt = 0; kt < NT; kt++) {
    int cur = kt & 1;
    __syncthreads();

    bf16x8 ka, kb2, va, vb;
    if (kt + 1 < NT) {
      const bf16* Kn = Kp + (size_t)(kt + 1) * 64 * DH;
      const bf16* Vn = Vp + (size_t)(kt + 1) * 64;
      ka  = *(const bf16x8*)(Kn + (size_t)srow * DH + scc);
      kb2 = *(const bf16x8*)(Kn + (size_t)(32 + srow) * DH + scc);
      va  = *(const bf16x8*)(Vn + (size_t)srow * S_ + scc);
      vb  = *(const bf16x8*)(Vn + (size_t)(32 + srow) * S_ + scc);
    }

    bf16x8 vf[4][2];
    #pragma unroll
    for (int td = 0; td < 4; td++)
      #pragma unroll
      for (int ks = 0; ks < 2; ks++)
        vf[td][ks] = *(const bf16x8*)(Vs[cur] + (td * 16 + l16) * LDK + ks * 32 + quad * 8);

    #pragma unroll
    for (int hh = 0; hh < 2; hh++) {
      #pragma unroll
      for (int kq2 = 0; kq2 < 2; kq2++) {
        int kq = hh * 2 + kq2;
        bf16x8 kfr[2];
        #pragma unroll
        for (int ks = 0; ks < 2; ks++)
          kfr[ks] = *(const bf16x8*)(Ks[cur] + (kq * 16 + l16) * LDK + ks * 32 + quad * 8);
        #pragma unroll
        for (int nq = 0; nq < 4; nq++) {
          f32x4 st = {};
          st = __builtin_amdgcn_mfma_f32_16x16x32_bf16(kfr[0], qf[nq][0], st, 0, 0, 0);
          st = __builtin_amdgcn_mfma_f32_16x16x32_bf16(kfr[1], qf[nq][1], st, 0, 0, 0);
          bf16x4 pk;
          #pragma unroll
          for (int r = 0; r < 4; r++) pk[r] = (bf16)__builtin_amdgcn_exp2f(st[r]);
          *(bf16x4*)(&Ps[wave][(nq * 16 + l16) * LDP + kq2 * 16 + quad * 4]) = pk;
        }
      }
      #pragma unroll
      for (int nq = 0; nq < 4; nq++) {
        bf16x8 pf = *(const bf16x8*)(&Ps[wave][(nq * 16 + l16) * LDP + quad * 8]);
        oden[nq] = __builtin_amdgcn_mfma_f32_16x16x32_bf16(pf, onesf, oden[nq], 0, 0, 0);
        #pragma unroll
        for (int td = 0; td < 4; td++)
          o[nq][td] = __builtin_amdgcn_mfma_f32_16x16x32_bf16(pf, vf[td][hh], o[nq][td], 0, 0, 0);
      }
    }

    if (kt + 1 < NT) {
      int nxt = cur ^ 1;
      *(bf16x8*)(Ks[nxt] + srow * LDK + scc)        = ka;
      *(bf16x8*)(Ks[nxt] + (32 + srow) * LDK + scc) = kb2;
      *(bf16x8*)(Vs[nxt] + srow * LDK + scc)        = va;
      *(bf16x8*)(Vs[nxt] + (32 + srow) * LDK + scc) = vb;
    }
  }

  #pragma unroll
  for (int nq = 0; nq < 4; nq++) {
    #pragma unroll
    for (int r = 0; r < 4; r++) {
      float inv = 1.0f / oden[nq][r];
      int q = q0 + nq * 16 + quad * 4 + r;
      #pragma unroll
      for (int td = 0; td < 4; td++) {
        int dd = td * 16 + l16;
        ctx[((size_t)(b * S_) + q) * D_ + h * DH + dd] = (bf16)(o[nq][td][r] * inv);
      }
    }
  }
}

// -------------------- host launch --------------------
extern "C" void kernel_launch(void* const* d_in, const int* in_sizes, int n_in,
                              void* d_out, int out_size, void* d_ws, size_t ws_size,
                              hipStream_t stream) {
  (void)in_sizes; (void)n_in; (void)out_size; (void)ws_size;
  const float* hidden = (const float*)d_in[0];
  const float* w_qkv  = (const float*)d_in[1];
  const float* w_out  = (const float*)d_in[2];
  float* out = (float*)d_out;

  char* ws = (char*)d_ws;
  size_t off = 0;
  bf16* hb    = (bf16*)(ws + off); off += (size_t)M_ * D_ * 2;      // hidden bf16 (reused as ctx)
  bf16* wqkvT = (bf16*)(ws + off); off += (size_t)3 * D_ * D_ * 2;  // [3072][1024]
  bf16* woutT = (bf16*)(ws + off); off += (size_t)D_ * D_ * 2;      // [1024][1024]
  bf16* Qb    = (bf16*)(ws + off); off += (size_t)M_ * D_ * 2;      // [BH][S][DH], pre-scaled
  bf16* Kb    = (bf16*)(ws + off); off += (size_t)M_ * D_ * 2;      // [BH][S][DH]
  bf16* Vtb   = (bf16*)(ws + off); off += (size_t)M_ * D_ * 2;      // [BH][DH][S]
  bf16* ctxb  = hb;  // alias: hb dead after gemm_qkv

  cvt_f32_bf16<<<(M_ * D_ / 4 + 255) / 256, 256, 0, stream>>>(hidden, hb, M_ * D_);
  transpose_cvt2<<<dim3(128, D_ / 32), dim3(32, 8), 0, stream>>>(w_qkv, w_out, wqkvT, woutT);
  gemm_qkv<<<dim3(3 * D_ / 128, M_ / 128), 256, 0, stream>>>(hb, wqkvT, Qb, Kb, Vtb);
  attn<<<dim3(BH_, S_ / 256), 256, 0, stream>>>(Qb, Kb, Vtb, ctxb);
  gemm_out<<<dim3(D_ / 128, M_ / 128), 256, 0, stream>>>(ctxb, woutT, out);
}

// Round 7
// 251.373 us; speedup vs baseline: 1.1164x; 1.1164x over previous
//
#include <hip/hip_runtime.h>
#include <hip/hip_bf16.h>
#include <math.h>

typedef __bf16 bf16;
typedef __bf16 bf16x4 __attribute__((ext_vector_type(4)));
typedef __bf16 bf16x8 __attribute__((ext_vector_type(8)));
typedef float  f32x4  __attribute__((ext_vector_type(4)));

#define B_  4
#define S_  2048
#define D_  1024
#define H_  16
#define DH  64
#define M_  (B_*S_)      // 8192
#define BH_ (B_*H_)      // 64

// 1/sqrt(64) * log2(e): folded into Q so attn uses exp2 directly
#define QSCALE 0.18033688011112042f

__device__ __forceinline__ void glds16(const bf16* g, bf16* l) {
  __builtin_amdgcn_global_load_lds((const __attribute__((address_space(1))) void*)g,
                                   (__attribute__((address_space(3))) void*)l, 16, 0, 0);
}

// -------------------- prep: hidden fp32->bf16 + both weight transposes, ONE launch ----------
// blocks [0, 8192): cvt hidden; [8192, 8192+96*32): w_qkv transpose; rest: w_out transpose.
__global__ __launch_bounds__(256) void prep(const float* __restrict__ hidden, bf16* __restrict__ hb,
                                            const float* __restrict__ wqkv, const float* __restrict__ wout,
                                            bf16* __restrict__ wqkvT, bf16* __restrict__ woutT) {
  int bx = blockIdx.x, tid = threadIdx.x;
  if (bx < 8192) {
    int i = (bx * 256 + tid) * 4;
    float4 v = *(const float4*)(hidden + i);
    bf16x4 o = { (bf16)v.x, (bf16)v.y, (bf16)v.z, (bf16)v.w };
    *(bf16x4*)(hb + i) = o;
    return;
  }
  __shared__ float tile[32][33];
  int t = bx - 8192;
  const float* in; bf16* out; int C, c0, r0;
  if (t < 96 * 32) { in = wqkv; out = wqkvT; C = 3072; c0 = (t % 96) * 32; r0 = (t / 96) * 32; }
  else { t -= 96 * 32;  in = wout; out = woutT; C = 1024; c0 = (t % 32) * 32; r0 = (t / 32) * 32; }
  int tx = tid & 31, ty = tid >> 5;
  #pragma unroll
  for (int i = ty; i < 32; i += 8) tile[i][tx] = in[(size_t)(r0 + i) * C + c0 + tx];
  __syncthreads();
  #pragma unroll
  for (int i = ty; i < 32; i += 8) out[(size_t)(c0 + i) * D_ + r0 + tx] = (bf16)tile[tx][i];
}

// -------------------- GEMM core: C[128x128] += A[128xK]*Bt[128xK]^T, BK=64 ------------------
// R5's proven 16x16 core, with BK=64 staged as TWO stacked 128x32 sub-tiles (each sub-tile
// byte-identical to the R5 BK=32 layout: LDA2=32, rows 64B, frag read row*64B + quad*16B ->
// measured-good ~2 cyc/read conflict profile). Halves barrier count: 16 iters instead of 32.
#define LDA2 32
#define SUB  (128 * LDA2)   // elements per k-half sub-tile

__device__ __forceinline__ void gemm_core(const bf16* __restrict__ A, const bf16* __restrict__ Bt,
                                          int m0, int n0, bf16* As, bf16* Bs,
                                          int tid, f32x4 acc[4][4]) {
  int wave = tid >> 6, lane = tid & 63, quad = lane >> 4, l16 = lane & 15;
  int wm = (wave >> 1) * 64, wn = (wave & 1) * 64;
  int lr = lane >> 2, lc = (lane & 3) * 8;              // lane -> (row, col8) within 16-row chunk
  const bf16* gA = A  + (size_t)(m0 + wave * 32 + lr) * D_ + lc;
  const bf16* gB = Bt + (size_t)(n0 + wave * 32 + lr) * D_ + lc;
  bf16* lA = As + wave * 32 * LDA2;                     // wave-uniform LDS bases
  bf16* lB = Bs + wave * 32 * LDA2;
  for (int k0 = 0; k0 < D_; k0 += 64) {
    #pragma unroll
    for (int h = 0; h < 2; h++) {
      int kk = k0 + h * 32;
      glds16(gA + kk,           lA + h * SUB);
      glds16(gA + kk + 16 * D_, lA + h * SUB + 16 * LDA2);
      glds16(gB + kk,           lB + h * SUB);
      glds16(gB + kk + 16 * D_, lB + h * SUB + 16 * LDA2);
    }
    __syncthreads();
    #pragma unroll
    for (int h = 0; h < 2; h++) {
      bf16x8 af[4], bff[4];
      #pragma unroll
      for (int i = 0; i < 4; i++) af[i]  = *(const bf16x8*)(As + h * SUB + (wm + i * 16 + l16) * LDA2 + quad * 8);
      #pragma unroll
      for (int j = 0; j < 4; j++) bff[j] = *(const bf16x8*)(Bs + h * SUB + (wn + j * 16 + l16) * LDA2 + quad * 8);
      #pragma unroll
      for (int i = 0; i < 4; i++)
        #pragma unroll
        for (int j = 0; j < 4; j++)
          acc[i][j] = __builtin_amdgcn_mfma_f32_16x16x32_bf16(af[i], bff[j], acc[i][j], 0, 0, 0);
    }
    __syncthreads();
  }
}

// GEMM1: qkv = hidden @ w_qkv. Q gets QSCALE folded in; V written transposed.
__global__ __launch_bounds__(256) void gemm_qkv(const bf16* __restrict__ A, const bf16* __restrict__ Bt,
                                                bf16* __restrict__ Qb, bf16* __restrict__ Kb,
                                                bf16* __restrict__ Vtb) {
  __shared__ __attribute__((aligned(16))) bf16 As[2 * SUB];
  __shared__ __attribute__((aligned(16))) bf16 Bs[2 * SUB];
  int tid = threadIdx.x;
  int m0 = blockIdx.y * 128, n0 = blockIdx.x * 128;
  f32x4 acc[4][4] = {};
  gemm_core(A, Bt, m0, n0, As, Bs, tid, acc);
  int wave = tid >> 6, lane = tid & 63, quad = lane >> 4, l16 = lane & 15;
  int wm = (wave >> 1) * 64, wn = (wave & 1) * 64;
  int which = n0 >> 10;                 // 0=Q 1=K 2=V, block-uniform
  if (which == 2) {
    #pragma unroll
    for (int i = 0; i < 4; i++) {
      int mb = m0 + wm + i * 16 + quad * 4;
      int b = mb >> 11, s = mb & 2047;
      #pragma unroll
      for (int j = 0; j < 4; j++) {
        int n = n0 + wn + j * 16 + l16;
        int h = (n >> 6) & 15, dd = n & 63;
        bf16x4 v4 = { (bf16)acc[i][j][0], (bf16)acc[i][j][1], (bf16)acc[i][j][2], (bf16)acc[i][j][3] };
        *(bf16x4*)(Vtb + ((size_t)(b * H_ + h) * DH + dd) * S_ + s) = v4;
      }
    }
  } else {
    bf16* dst = (which == 0) ? Qb : Kb;
    float sc = (which == 0) ? QSCALE : 1.0f;
    #pragma unroll
    for (int i = 0; i < 4; i++) {
      #pragma unroll
      for (int j = 0; j < 4; j++) {
        int n = n0 + wn + j * 16 + l16;
        int h = (n >> 6) & 15, dd = n & 63;
        #pragma unroll
        for (int r = 0; r < 4; r++) {
          int m = m0 + wm + i * 16 + quad * 4 + r;
          int b = m >> 11, s = m & 2047;
          dst[(((size_t)(b * H_ + h)) * S_ + s) * DH + dd] = (bf16)(acc[i][j][r] * sc);
        }
      }
    }
  }
}

// GEMM2: out = ctx @ w_out, fp32 output. Grid x=m (consecutive blocks share the
// B-panel within an XCD for L2 locality).
__global__ __launch_bounds__(256) void gemm_out(const bf16* __restrict__ A, const bf16* __restrict__ Bt,
                                                float* __restrict__ C) {
  __shared__ __attribute__((aligned(16))) bf16 As[2 * SUB];
  __shared__ __attribute__((aligned(16))) bf16 Bs[2 * SUB];
  int tid = threadIdx.x;
  int m0 = blockIdx.x * 128, n0 = blockIdx.y * 128;
  f32x4 acc[4][4] = {};
  gemm_core(A, Bt, m0, n0, As, Bs, tid, acc);
  int wave = tid >> 6, lane = tid & 63, quad = lane >> 4, l16 = lane & 15;
  int wm = (wave >> 1) * 64, wn = (wave & 1) * 64;
  #pragma unroll
  for (int i = 0; i < 4; i++)
    #pragma unroll
    for (int j = 0; j < 4; j++) {
      int n = n0 + wn + j * 16 + l16;
      #pragma unroll
      for (int r = 0; r < 4; r++) {
        int m = m0 + wm + i * 16 + quad * 4 + r;
        C[(size_t)m * D_ + n] = acc[i][j][r];
      }
    }
}

// -------------------- flash attention (EXACT R5: 84us known-good; control for this round) ----
#define LDK 72   // K/V tiles: 144B rows
#define LDP 40   // Ps half-panels: 80B rows
#define NT  (S_ / 64)

__global__ __launch_bounds__(256, 2) void attn(const bf16* __restrict__ Qb, const bf16* __restrict__ Kb,
                                               const bf16* __restrict__ Vtb, bf16* __restrict__ ctx) {
  __shared__ __attribute__((aligned(16))) bf16 Ks[2][64 * LDK];   // [buf][key][dd]
  __shared__ __attribute__((aligned(16))) bf16 Vs[2][64 * LDK];   // [buf][dd][key]
  __shared__ __attribute__((aligned(16))) bf16 Ps[4][64 * LDP];   // per-wave P half: [q(64)][key(32)]
  int tid = threadIdx.x;
  int wave = tid >> 6, lane = tid & 63, quad = lane >> 4, l16 = lane & 15;
  int bh = blockIdx.x;                  // x-major: XCD = bh % 8 -> K/V working set stays in one L2
  int b = bh >> 4, h = bh & 15;
  int q0 = blockIdx.y * 256 + wave * 64;
  const bf16* Qp = Qb  + (size_t)bh * S_ * DH;
  const bf16* Kp = Kb  + (size_t)bh * S_ * DH;
  const bf16* Vp = Vtb + (size_t)bh * DH * S_;

  int srow = tid >> 3, scc = (tid & 7) << 3;

  bf16x8 qf[4][2];
  #pragma unroll
  for (int nq = 0; nq < 4; nq++)
    #pragma unroll
    for (int ks = 0; ks < 2; ks++)
      qf[nq][ks] = *(const bf16x8*)(Qp + (size_t)(q0 + nq * 16 + l16) * DH + ks * 32 + quad * 8);

  bf16 one1 = (bf16)1.0f;
  bf16x8 onesf = { one1, one1, one1, one1, one1, one1, one1, one1 };

  f32x4 o[4][4] = {};       // o[nq][td]: row q = quad*4+r, col dd = td*16+l16
  f32x4 oden[4] = {};       // denom(q), same row mapping

  {
    bf16x8 k0a = *(const bf16x8*)(Kp + (size_t)srow * DH + scc);
    bf16x8 k0b = *(const bf16x8*)(Kp + (size_t)(32 + srow) * DH + scc);
    bf16x8 v0a = *(const bf16x8*)(Vp + (size_t)srow * S_ + scc);
    bf16x8 v0b = *(const bf16x8*)(Vp + (size_t)(32 + srow) * S_ + scc);
    *(bf16x8*)(Ks[0] + srow * LDK + scc)        = k0a;
    *(bf16x8*)(Ks[0] + (32 + srow) * LDK + scc) = k0b;
    *(bf16x8*)(Vs[0] + srow * LDK + scc)        = v0a;
    *(bf16x8*)(Vs[0] + (32 + srow) * LDK + scc) = v0b;
  }

  for (int kt = 0; kt < NT; kt++) {
    int cur = kt & 1;
    __syncthreads();

    bf16x8 ka, kb2, va, vb;
    if (kt + 1 < NT) {
      const bf16* Kn = Kp + (size_t)(kt + 1) * 64 * DH;
      const bf16* Vn = Vp + (size_t)(kt + 1) * 64;
      ka  = *(const bf16x8*)(Kn + (size_t)srow * DH + scc);
      kb2 = *(const bf16x8*)(Kn + (size_t)(32 + srow) * DH + scc);
      va  = *(const bf16x8*)(Vn + (size_t)srow * S_ + scc);
      vb  = *(const bf16x8*)(Vn + (size_t)(32 + srow) * S_ + scc);
    }

    bf16x8 vf[4][2];
    #pragma unroll
    for (int td = 0; td < 4; td++)
      #pragma unroll
      for (int ks = 0; ks < 2; ks++)
        vf[td][ks] = *(const bf16x8*)(Vs[cur] + (td * 16 + l16) * LDK + ks * 32 + quad * 8);

    #pragma unroll
    for (int hh = 0; hh < 2; hh++) {
      #pragma unroll
      for (int kq2 = 0; kq2 < 2; kq2++) {
        int kq = hh * 2 + kq2;
        bf16x8 kfr[2];
        #pragma unroll
        for (int ks = 0; ks < 2; ks++)
          kfr[ks] = *(const bf16x8*)(Ks[cur] + (kq * 16 + l16) * LDK + ks * 32 + quad * 8);
        #pragma unroll
        for (int nq = 0; nq < 4; nq++) {
          f32x4 st = {};
          st = __builtin_amdgcn_mfma_f32_16x16x32_bf16(kfr[0], qf[nq][0], st, 0, 0, 0);
          st = __builtin_amdgcn_mfma_f32_16x16x32_bf16(kfr[1], qf[nq][1], st, 0, 0, 0);
          bf16x4 pk;
          #pragma unroll
          for (int r = 0; r < 4; r++) pk[r] = (bf16)__builtin_amdgcn_exp2f(st[r]);
          *(bf16x4*)(&Ps[wave][(nq * 16 + l16) * LDP + kq2 * 16 + quad * 4]) = pk;
        }
      }
      #pragma unroll
      for (int nq = 0; nq < 4; nq++) {
        bf16x8 pf = *(const bf16x8*)(&Ps[wave][(nq * 16 + l16) * LDP + quad * 8]);
        oden[nq] = __builtin_amdgcn_mfma_f32_16x16x32_bf16(pf, onesf, oden[nq], 0, 0, 0);
        #pragma unroll
        for (int td = 0; td < 4; td++)
          o[nq][td] = __builtin_amdgcn_mfma_f32_16x16x32_bf16(pf, vf[td][hh], o[nq][td], 0, 0, 0);
      }
    }

    if (kt + 1 < NT) {
      int nxt = cur ^ 1;
      *(bf16x8*)(Ks[nxt] + srow * LDK + scc)        = ka;
      *(bf16x8*)(Ks[nxt] + (32 + srow) * LDK + scc) = kb2;
      *(bf16x8*)(Vs[nxt] + srow * LDK + scc)        = va;
      *(bf16x8*)(Vs[nxt] + (32 + srow) * LDK + scc) = vb;
    }
  }

  #pragma unroll
  for (int nq = 0; nq < 4; nq++) {
    #pragma unroll
    for (int r = 0; r < 4; r++) {
      float inv = 1.0f / oden[nq][r];
      int q = q0 + nq * 16 + quad * 4 + r;
      #pragma unroll
      for (int td = 0; td < 4; td++) {
        int dd = td * 16 + l16;
        ctx[((size_t)(b * S_) + q) * D_ + h * DH + dd] = (bf16)(o[nq][td][r] * inv);
      }
    }
  }
}

// -------------------- host launch --------------------
extern "C" void kernel_launch(void* const* d_in, const int* in_sizes, int n_in,
                              void* d_out, int out_size, void* d_ws, size_t ws_size,
                              hipStream_t stream) {
  (void)in_sizes; (void)n_in; (void)out_size; (void)ws_size;
  const float* hidden = (const float*)d_in[0];
  const float* w_qkv  = (const float*)d_in[1];
  const float* w_out  = (const float*)d_in[2];
  float* out = (float*)d_out;

  char* ws = (char*)d_ws;
  size_t off = 0;
  bf16* hb    = (bf16*)(ws + off); off += (size_t)M_ * D_ * 2;      // hidden bf16 (reused as ctx)
  bf16* wqkvT = (bf16*)(ws + off); off += (size_t)3 * D_ * D_ * 2;  // [3072][1024]
  bf16* woutT = (bf16*)(ws + off); off += (size_t)D_ * D_ * 2;      // [1024][1024]
  bf16* Qb    = (bf16*)(ws + off); off += (size_t)M_ * D_ * 2;      // [BH][S][DH], pre-scaled
  bf16* Kb    = (bf16*)(ws + off); off += (size_t)M_ * D_ * 2;      // [BH][S][DH]
  bf16* Vtb   = (bf16*)(ws + off); off += (size_t)M_ * D_ * 2;      // [BH][DH][S]
  bf16* ctxb  = hb;  // alias: hb dead after gemm_qkv

  prep<<<8192 + 96 * 32 + 32 * 32, 256, 0, stream>>>(hidden, hb, w_qkv, w_out, wqkvT, woutT);
  gemm_qkv<<<dim3(3 * D_ / 128, M_ / 128), 256, 0, stream>>>(hb, wqkvT, Qb, Kb, Vtb);
  attn<<<dim3(BH_, S_ / 256), 256, 0, stream>>>(Qb, Kb, Vtb, ctxb);
  gemm_out<<<dim3(M_ / 128, D_ / 128), 256, 0, stream>>>(ctxb, woutT, out);
}